// Round 20
// baseline (212.100 us; speedup 1.0000x reference)
//
#include <hip/hip_runtime.h>
#include <hip/hip_fp16.h>
#include <math.h>

// Problem constants (fixed by the reference).
constexpr int B_ = 2, T_ = 3, H_ = 128, W_ = 128, C_ = 128;
constexpr int HEADS_ = 8, D_ = 16, CK_ = 128;
constexpr int RY_ = 2, RX_ = 2, PH_ = 5, PW_ = 5, S_ = 25;
constexpr int NTOK = B_ * T_ * H_ * W_;   // 98304 tokens

typedef float     f32x4 __attribute__((ext_vector_type(4)));
typedef _Float16  f16x2 __attribute__((ext_vector_type(2)));
typedef _Float16  f16x4 __attribute__((ext_vector_type(4)));
typedef _Float16  f16x8 __attribute__((ext_vector_type(8)));

static __device__ __forceinline__ f32x4 mfma16(f16x4 a, f16x4 b, f32x4 c) {
#if __has_builtin(__builtin_amdgcn_mfma_f32_16x16x16f16)
  return __builtin_amdgcn_mfma_f32_16x16x16f16(a, b, c, 0, 0, 0);
#else
  asm volatile("v_mfma_f32_16x16x16_f16 %0, %1, %2, %0" : "+v"(c) : "v"(a), "v"(b));
  return c;
#endif
}

union U32H2 { unsigned u; f16x2 h; __half2 hh; };

static __device__ __forceinline__ f16x2 pkrtz(float a, float b) {
  return __builtin_bit_cast(f16x2, __builtin_amdgcn_cvt_pkrtz(a, b));
}

static __device__ __forceinline__ unsigned pk_exp2(f16x2 x) {
  U32H2 in, out;
  in.h = x;
  out.hh = h2exp2(in.hh);      // 2x v_exp_f16
  return out.u;
}

// LDS layout for the fused attention kernel (dynamic: 133,120 B)
constexpr int KV_STRIDE = 136;                    // f16 elems per row (128 + 8 pad)
constexpr int KV_ELEMS  = 192 * KV_STRIDE;        // 26112
constexpr int QE_ELEMS  = 8 * 64 * 26;            // 13312
constexpr size_t SMEM_BYTES = (size_t)(2 * KV_ELEMS + QE_ELEMS) * 2 + 16 * 2 * 16 * 4;

// ---------------------------------------------------------------------------
// Kernel P: pack weights fp16 transposed; spatial_emb fp16 padded [32][128];
// tv[t][n] = temp_emb[t] @ Wv.  WT = [Wq^T; Wk^T; Wv^T] as [384][128].
// ---------------------------------------------------------------------------
__global__ __launch_bounds__(256) void prep(
    const float* __restrict__ Wq, const float* __restrict__ Wk,
    const float* __restrict__ Wv, const float* __restrict__ Wo,
    const float* __restrict__ sp, const float* __restrict__ te,
    _Float16* __restrict__ WT, _Float16* __restrict__ WoT,
    _Float16* __restrict__ spH, float* __restrict__ tv)
{
  const int idx = blockIdx.x * 256 + threadIdx.x;
  if (idx < 49152) {
    const int m = idx >> 14, j = idx & 16383, n = j >> 7, k = j & 127;
    const float* Wm = (m == 0) ? Wq : ((m == 1) ? Wk : Wv);
    WT[idx] = (_Float16)Wm[k * 128 + n];
  } else if (idx < 65536) {
    const int j = idx - 49152, n = j >> 7, k = j & 127;
    WoT[j] = (_Float16)Wo[k * 128 + n];
  } else if (idx < 69632) {
    const int j = idx - 65536, s = j >> 7, c = j & 127;
    spH[j] = (s < 25) ? (_Float16)sp[s * 128 + c] : (_Float16)0.f;
  } else if (idx < 70016) {
    const int j = idx - 69632, t = j >> 7, n = j & 127;
    float a = 0.f;
    for (int c = 0; c < 128; ++c) a += te[t * 128 + c] * Wv[c * 128 + n];
    tv[j] = a;
  }
}

// ---------------------------------------------------------------------------
// Kernel A: QKV via MFMA (R13/R17 structure, ~45us measured).
// ---------------------------------------------------------------------------
__global__ __launch_bounds__(256, 3) void qkv_mfma(
    const float* __restrict__ values, const _Float16* __restrict__ WT,
    const float* __restrict__ temp_emb, const float* __restrict__ spatial_emb,
    const float* __restrict__ tv,
    _Float16* __restrict__ Qh, _Float16* __restrict__ Kh, _Float16* __restrict__ Vh)
{
  __shared__ __align__(16) _Float16 kin_s[64][140];
  const int tid = threadIdx.x;
  const int tok0 = blockIdx.x * 64;
  const int t = (tok0 >> 14) % T_;

  for (int i = tid; i < 64 * 32; i += 256) {
    const int tk = i >> 5, cg = i & 31;
    const float4 v = *(const float4*)&values[(size_t)(tok0 + tk) * C_ + cg * 4];
    const float4 e = *(const float4*)&temp_emb[t * C_ + cg * 4];
    f16x4 kv;
    kv[0] = (_Float16)(v.x + e.x); kv[1] = (_Float16)(v.y + e.y);
    kv[2] = (_Float16)(v.z + e.z); kv[3] = (_Float16)(v.w + e.w);
    *(f16x4*)&kin_s[tk][cg * 4] = kv;
  }

  const int l = tid & 63, w = tid >> 6, l15 = l & 15, g = l >> 4;
  const _Float16* Wbase = WT + (size_t)(w * 96) * 128;

  f16x4 acur[6], anxt[6];
#pragma unroll
  for (int j = 0; j < 6; ++j)
    acur[j] = *(const f16x4*)&Wbase[(size_t)(j * 16 + l15) * 128 + 4 * g];

  __syncthreads();

  f32x4 acc[6][4];
#pragma unroll
  for (int j = 0; j < 6; ++j)
#pragma unroll
    for (int tt = 0; tt < 4; ++tt) acc[j][tt] = (f32x4){0.f, 0.f, 0.f, 0.f};

#pragma unroll
  for (int kc = 0; kc < 8; ++kc) {
    if (kc < 7) {
      const int kon = (kc + 1) * 16 + 4 * g;
#pragma unroll
      for (int j = 0; j < 6; ++j)
        anxt[j] = *(const f16x4*)&Wbase[(size_t)(j * 16 + l15) * 128 + kon];
    }
    const int ko = kc * 16 + 4 * g;
    f16x4 bfr[4];
#pragma unroll
    for (int tt = 0; tt < 4; ++tt)
      bfr[tt] = *(const f16x4*)&kin_s[tt * 16 + l15][ko];
#pragma unroll
    for (int j = 0; j < 6; ++j)
#pragma unroll
      for (int tt = 0; tt < 4; ++tt)
        acc[j][tt] = mfma16(acur[j], bfr[tt], acc[j][tt]);
#pragma unroll
    for (int j = 0; j < 6; ++j) acur[j] = anxt[j];
  }

  constexpr float CSC = 0.25f * 1.44269504088896f;
#pragma unroll
  for (int j = 0; j < 6; ++j) {
    const int ntile = w * 6 + j;
    const int ch0 = (ntile & 7) * 16 + 4 * g;
#pragma unroll
    for (int tt = 0; tt < 4; ++tt) {
      const int tok = tok0 + tt * 16 + l15;
      const size_t o = (size_t)tok * CK_ + ch0;
      f16x4 r;
      if (ntile < 8) {
        const int x = tok & 127, y = (tok >> 7) & 127;
        const int cy = min(max(y, RY_), H_ - 1 - RY_);
        const int cx = min(max(x, RX_), W_ - 1 - RX_);
        const int qsp = (y - cy + RY_) * PW_ + (x - cx + RX_);
        const float4 e = *(const float4*)&spatial_emb[qsp * CK_ + ch0];
        r[0] = (_Float16)((acc[j][tt][0] + e.x) * CSC);
        r[1] = (_Float16)((acc[j][tt][1] + e.y) * CSC);
        r[2] = (_Float16)((acc[j][tt][2] + e.z) * CSC);
        r[3] = (_Float16)((acc[j][tt][3] + e.w) * CSC);
        *(f16x4*)&Qh[o] = r;
      } else if (ntile < 16) {
        r[0] = (_Float16)acc[j][tt][0]; r[1] = (_Float16)acc[j][tt][1];
        r[2] = (_Float16)acc[j][tt][2]; r[3] = (_Float16)acc[j][tt][3];
        *(f16x4*)&Kh[o] = r;
      } else {
        const float4 tve = *(const float4*)&tv[t * 128 + ch0];
        r[0] = (_Float16)(acc[j][tt][0] - tve.x);
        r[1] = (_Float16)(acc[j][tt][1] - tve.y);
        r[2] = (_Float16)(acc[j][tt][2] - tve.z);
        r[3] = (_Float16)(acc[j][tt][3] - tve.w);
        *(f16x4*)&Vh[o] = r;
      }
    }
  }
}

// ---------------------------------------------------------------------------
// Kernel B: FUSED attention + out-projection (R18/R19 structure). ONE change:
// __attribute__((amdgpu_waves_per_eu(4,4))) — pins the occupancy target to
// exactly 4 waves/EU (= the 1 block/CU that 130KB dynamic LDS forces anyway),
// giving a 128-VGPR budget. R18/R19's launch_bounds only set the MINIMUM
// waves; with extern __shared__ the compiler assumed LDS=0 and aimed for 8
// waves/EU -> 64 VGPR -> 12MB scratch spill. Tripwires: VGPR>=90, WRITE~49MB.
// ---------------------------------------------------------------------------
__global__ __launch_bounds__(1024)
__attribute__((amdgpu_waves_per_eu(4, 4)))
void attn_fused(
    const _Float16* __restrict__ Q, const _Float16* __restrict__ K,
    const _Float16* __restrict__ V, const _Float16* __restrict__ spH,
    const _Float16* __restrict__ WoT, float* __restrict__ out)
{
  extern __shared__ __align__(16) _Float16 smem[];
  _Float16* K_s  = smem;                 // [192][136]
  _Float16* V_s  = K_s + KV_ELEMS;       // [192][136]
  _Float16* qe_s = V_s + KV_ELEMS;       // [8][64][26]; slot25 = -30000
  float*    l_s  = (float*)(qe_s + QE_ELEMS);  // [16][2][16]
  _Float16* ck_s = K_s;                  // epilogue reuse: [64][136]

  const int tid = threadIdx.x;
  const int bid0 = blockIdx.x;
  const int tile = (bid0 & 7) * 192 + (bid0 >> 3);  // bijective: 1536 = 8x192
  const int tx = tile & 15, ty = (tile >> 4) & 15, img = tile >> 8;
  const int b = img / 3;
  const int y0 = ty * 8, x0 = tx * 8;
  const int rowbase = max(y0, 2) - 2;
  const int colbase = max(x0, 2) - 2;
  const int tokbase = img * 16384 + y0 * 128 + x0;

  const int wv5 = tid >> 6;              // 0..15
  const int hq  = wv5 >> 2;              // head quarter 0..3
  const int wvq = wv5 & 3;               // wave within quarter
  const int chb = hq * 32;
  const int l = tid & 63, l15 = l & 15, g = l >> 4;
  const int q_glob = wvq * 16 + l15;
  const int qy = 2 * wvq + (l15 >> 3), qx = l15 & 7;
  const int y = y0 + qy, x = x0 + qx;
  const int tok = tokbase + qy * 128 + qx;
  const int cy = min(max(y, 2), 125), cx = min(max(x, 2), 125);
  const int myryc = cy - rowbase;
  const int rxc = cx - colbase;
  const int dxpbase = 4 * g - rxc + 2;

  const int rycA = min(max(y0 + 2 * wvq,     2), 125) - rowbase;
  const int rycB = min(max(y0 + 2 * wvq + 1, 2), 125) - rowbase;
  const int rymin = min(min(rycA, rycB) - 2, 6);

  bool vx[4];
#pragma unroll
  for (int i = 0; i < 4; ++i) vx[i] = (unsigned)(dxpbase + i) <= 4u;

  // ---- staging offsets: 192 rows x 32 ch-groups, 6 chunks/thread ----
  int poff[6], ldoff[6];
#pragma unroll
  for (int it = 0; it < 6; ++it) {
    const int idx = tid + it * 1024;
    const int row = idx >> 5, cg = idx & 31;
    const int ny = min(rowbase + (row >> 4), 127);
    const int nx = min(colbase + (row & 15), 127);
    poff[it] = (ny * 128 + nx) * CK_ + cg * 4;
    ldoff[it] = row * KV_STRIDE + cg * 4;
  }
  const size_t imgstep = (size_t)16384 * CK_;
  const _Float16* Kp = K + (size_t)(b * 3) * imgstep;
  const _Float16* Vp = V + (size_t)(b * 3) * imgstep;

  f16x4 kpre[6], vpre[6];
#pragma unroll
  for (int it = 0; it < 6; ++it) {
    kpre[it] = *(const f16x4*)&Kp[poff[it]];
    vpre[it] = *(const f16x4*)&Vp[poff[it]];
  }

  f16x4 qfrag[2];
#pragma unroll
  for (int h = 0; h < 2; ++h)
    qfrag[h] = *(const f16x4*)&Q[(size_t)tok * CK_ + chb + h * 16 + 4 * g];

  // qe[hg][q][s] table (per-wave-private rows)
#pragma unroll
  for (int h = 0; h < 2; ++h) {
    const int qrow = ((hq * 2 + h) * 64 + q_glob) * 26;
#pragma unroll
    for (int mt = 0; mt < 2; ++mt) {
      const f16x4 a = *(const f16x4*)&spH[(size_t)(mt * 16 + l15) * 128 + chb + h * 16 + 4 * g];
      f32x4 c = {0.f, 0.f, 0.f, 0.f};
      c = mfma16(a, qfrag[h], c);
      const int s0w = mt * 16 + 4 * g;
      if (mt == 0 || g < 2) {
        U32H2 p01, p23;
        p01.h = pkrtz(c[0], c[1]);
        p23.h = pkrtz(c[2], c[3]);
        *(unsigned*)&qe_s[qrow + s0w]     = p01.u;
        *(unsigned*)&qe_s[qrow + s0w + 2] = p23.u;
      } else if (g == 2) {
        qe_s[qrow + 24] = (_Float16)c[0];
      }
    }
  }
  if (g == 0) {
    qe_s[((hq * 2 + 0) * 64 + q_glob) * 26 + 25] = (_Float16)(-30000.0f);
    qe_s[((hq * 2 + 1) * 64 + q_glob) * 26 + 25] = (_Float16)(-30000.0f);
  }

  f32x4 o_acc[2];
  float l_acc[2];
#pragma unroll
  for (int h = 0; h < 2; ++h) { o_acc[h] = (f32x4){0.f, 0.f, 0.f, 0.f}; l_acc[h] = 0.f; }

  const f16x2 ones2 = {(_Float16)1.f, (_Float16)1.f};

#pragma unroll
  for (int t = 0; t < 3; ++t) {
    if (t) __syncthreads();
#pragma unroll
    for (int it = 0; it < 6; ++it) {
      *(f16x4*)&K_s[ldoff[it]] = kpre[it];
      *(f16x4*)&V_s[ldoff[it]] = vpre[it];
    }
    __syncthreads();
    if (t < 2) {
      const _Float16* Kt = Kp + (size_t)(t + 1) * imgstep;
      const _Float16* Vt = Vp + (size_t)(t + 1) * imgstep;
#pragma unroll
      for (int it = 0; it < 6; ++it) {
        kpre[it] = *(const f16x4*)&Kt[poff[it]];
        vpre[it] = *(const f16x4*)&Vt[poff[it]];
      }
    }

    __builtin_amdgcn_s_setprio(1);
    f16x4 wfr[2][6];
#pragma unroll
    for (int jj = 0; jj < 6; ++jj) {
      const int nt = rymin + jj;
      f32x4 c0 = {0.f, 0.f, 0.f, 0.f}, c1 = {0.f, 0.f, 0.f, 0.f};
      {
        const f16x4 a0 = *(const f16x4*)&K_s[(nt * 16 + l15) * KV_STRIDE + chb + 4 * g];
        const f16x4 a1 = *(const f16x4*)&K_s[(nt * 16 + l15) * KV_STRIDE + chb + 16 + 4 * g];
        c0 = mfma16(a0, qfrag[0], c0);
        c1 = mfma16(a1, qfrag[1], c1);
      }
      const int dyp = nt - myryc + 2;
      const bool vy = (unsigned)dyp <= 4u;
      const int s0 = dyp * 5 + dxpbase;
      int si[4];
#pragma unroll
      for (int i = 0; i < 4; ++i) si[i] = (vy && vx[i]) ? s0 + i : 25;
#pragma unroll
      for (int h = 0; h < 2; ++h) {
        const f32x4 c = h ? c1 : c0;
        const int qb = ((hq * 2 + h) * 64 + q_glob) * 26;
        U32H2 q01, q23;
        q01.u = (unsigned)(unsigned short)__builtin_bit_cast(short, qe_s[qb + si[0]])
              | ((unsigned)(unsigned short)__builtin_bit_cast(short, qe_s[qb + si[1]]) << 16);
        q23.u = (unsigned)(unsigned short)__builtin_bit_cast(short, qe_s[qb + si[2]])
              | ((unsigned)(unsigned short)__builtin_bit_cast(short, qe_s[qb + si[3]]) << 16);
        const f16x2 s01 = pkrtz(c[0], c[1]) + q01.h;
        const f16x2 s23 = pkrtz(c[2], c[3]) + q23.h;
        U32H2 p01, p23;
        p01.u = pk_exp2(s01);
        p23.u = pk_exp2(s23);
        l_acc[h] = __builtin_amdgcn_fdot2(p01.h, ones2, l_acc[h], false);
        l_acc[h] = __builtin_amdgcn_fdot2(p23.h, ones2, l_acc[h], false);
        union { unsigned u[2]; f16x4 v; } wu;
        wu.u[0] = p01.u; wu.u[1] = p23.u;
        wfr[h][jj] = wu.v;
      }
    }

#pragma unroll
    for (int h = 0; h < 2; ++h) {
#pragma unroll
      for (int jj = 0; jj < 6; ++jj) {
        const int nt = rymin + jj;
        f16x4 bv;
#pragma unroll
        for (int i = 0; i < 4; ++i)
          bv[i] = V_s[(nt * 16 + 4 * g + i) * KV_STRIDE + chb + h * 16 + l15];
        o_acc[h] = mfma16(wfr[h][jj], bv, o_acc[h]);
      }
    }
    __builtin_amdgcn_s_setprio(0);
  }

  // ---- normalize ----
#pragma unroll
  for (int h = 0; h < 2; ++h) {
    float lt = l_acc[h];
    lt += __shfl_xor(lt, 16);
    lt += __shfl_xor(lt, 32);
    if (l < 16) l_s[(wv5 * 2 + h) * 16 + l15] = 1.f / lt;
  }
  __syncthreads();                 // all PV done -> K_s reusable as ck_s

  // ---- write normalized context into ck_s [64 local tok][136] ----
#pragma unroll
  for (int h = 0; h < 2; ++h) {
#pragma unroll
    for (int i = 0; i < 4; ++i) {
      const int q = 4 * g + i;
      const float inv = l_s[(wv5 * 2 + h) * 16 + q];
      const int lt = wvq * 16 + (q >> 3) * 8 + (q & 7);   // local token 0..63
      ck_s[lt * KV_STRIDE + chb + h * 16 + l15] = (_Float16)(o_acc[h][i] * inv);
    }
  }
  __syncthreads();

  // ---- out = ck @ Wo (in-block): wave = N-tile (wv5>>1) x 2 tok-tiles ----
  const int n  = wv5 >> 1;
  const int w1 = wv5 & 1;
  f32x4 acc2[2];
  acc2[0] = (f32x4){0.f, 0.f, 0.f, 0.f};
  acc2[1] = (f32x4){0.f, 0.f, 0.f, 0.f};
#pragma unroll
  for (int kc = 0; kc < 8; ++kc) {
    const int ko = kc * 16 + 4 * g;
    const f16x4 a = *(const f16x4*)&WoT[(size_t)(n * 16 + l15) * 128 + ko];
#pragma unroll
    for (int j = 0; j < 2; ++j) {
      const int tt = w1 * 2 + j;
      const f16x4 bc = *(const f16x4*)&ck_s[(tt * 16 + l15) * KV_STRIDE + ko];
      acc2[j] = mfma16(a, bc, acc2[j]);
    }
  }
#pragma unroll
  for (int j = 0; j < 2; ++j) {
    const int tt = w1 * 2 + j;
    const int lt = tt * 16 + l15;
    const int gtok = tokbase + (lt >> 3) * 128 + (lt & 7);
    float4 ov;
    ov.x = acc2[j][0]; ov.y = acc2[j][1]; ov.z = acc2[j][2]; ov.w = acc2[j][3];
    *(float4*)&out[(size_t)gtok * C_ + n * 16 + 4 * g] = ov;
  }
}

// ---------------------------------------------------------------------------
extern "C" void kernel_launch(void* const* d_in, const int* in_sizes, int n_in,
                              void* d_out, int out_size, void* d_ws, size_t ws_size,
                              hipStream_t stream) {
    const float* values      = (const float*)d_in[0];
    const float* Wq          = (const float*)d_in[1];
    const float* Wk          = (const float*)d_in[2];
    const float* Wv          = (const float*)d_in[3];
    const float* Wo          = (const float*)d_in[4];
    const float* temp_emb    = (const float*)d_in[5];
    const float* spatial_emb = (const float*)d_in[6];
    float* out = (float*)d_out;

    const size_t NC = (size_t)NTOK * CK_;
    _Float16* Qh  = (_Float16*)d_ws;
    _Float16* Kh  = Qh  + NC;
    _Float16* Vh  = Kh  + NC;
    _Float16* WT  = Vh  + NC;          // [384][128]
    _Float16* WoT = WT  + 49152;       // [128][128]
    _Float16* spH = WoT + 16384;       // [32][128]
    float*    tv  = (float*)(spH + 4096);  // [3][128]

    // allow >64KB dynamic LDS (deterministic, not a stream op)
    (void)hipFuncSetAttribute((const void*)attn_fused,
                              hipFuncAttributeMaxDynamicSharedMemorySize,
                              (int)SMEM_BYTES);

    prep<<<274, 256, 0, stream>>>(Wq, Wk, Wv, Wo, spatial_emb, temp_emb,
                                  WT, WoT, spH, tv);
    qkv_mfma<<<NTOK / 64, 256, 0, stream>>>(values, WT, temp_emb, spatial_emb,
                                            tv, Qh, Kh, Vh);
    attn_fused<<<1536, 1024, SMEM_BYTES, stream>>>(Qh, Kh, Vh, spH, WoT, out);
}

// Round 21
// 169.875 us; speedup vs baseline: 1.2486x; 1.2486x over previous
//
#include <hip/hip_runtime.h>
#include <hip/hip_fp16.h>
#include <math.h>

// Problem constants (fixed by the reference).
constexpr int B_ = 2, T_ = 3, H_ = 128, W_ = 128, C_ = 128;
constexpr int HEADS_ = 8, D_ = 16, CK_ = 128;
constexpr int RY_ = 2, RX_ = 2, PH_ = 5, PW_ = 5, S_ = 25;
constexpr int NTOK = B_ * T_ * H_ * W_;   // 98304 tokens

typedef float     f32x4 __attribute__((ext_vector_type(4)));
typedef _Float16  f16x2 __attribute__((ext_vector_type(2)));
typedef _Float16  f16x4 __attribute__((ext_vector_type(4)));
typedef _Float16  f16x8 __attribute__((ext_vector_type(8)));

static __device__ __forceinline__ f32x4 mfma16(f16x4 a, f16x4 b, f32x4 c) {
#if __has_builtin(__builtin_amdgcn_mfma_f32_16x16x16f16)
  return __builtin_amdgcn_mfma_f32_16x16x16f16(a, b, c, 0, 0, 0);
#else
  asm volatile("v_mfma_f32_16x16x16_f16 %0, %1, %2, %0" : "+v"(c) : "v"(a), "v"(b));
  return c;
#endif
}

union U32H2 { unsigned u; f16x2 h; __half2 hh; };

// v_cvt_pkrtz_f16_f32 returns __fp16x2; bit-cast to our f16x2 (same bits).
static __device__ __forceinline__ f16x2 pkrtz(float a, float b) {
  return __builtin_bit_cast(f16x2, __builtin_amdgcn_cvt_pkrtz(a, b));
}

static __device__ __forceinline__ unsigned pk_exp2(f16x2 x) {
  U32H2 in, out;
  in.h = x;
  out.hh = h2exp2(in.hh);      // 2x v_exp_f16 (2^x per half)
  return out.u;
}

// ---------------------------------------------------------------------------
// Kernel P: pack weights fp16 transposed; spatial_emb fp16 padded [32][128];
// tv[t][n] = temp_emb[t] @ Wv (rank-1 correction so V shares the kin input).
// WT = [Wq^T; Wk^T; Wv^T] stacked as [384 n][128 k].
// ---------------------------------------------------------------------------
__global__ __launch_bounds__(256) void prep(
    const float* __restrict__ Wq, const float* __restrict__ Wk,
    const float* __restrict__ Wv, const float* __restrict__ Wo,
    const float* __restrict__ sp, const float* __restrict__ te,
    _Float16* __restrict__ WT, _Float16* __restrict__ WoT,
    _Float16* __restrict__ spH, float* __restrict__ tv)
{
  const int idx = blockIdx.x * 256 + threadIdx.x;
  if (idx < 49152) {
    const int m = idx >> 14, j = idx & 16383, n = j >> 7, k = j & 127;
    const float* Wm = (m == 0) ? Wq : ((m == 1) ? Wk : Wv);
    WT[idx] = (_Float16)Wm[k * 128 + n];
  } else if (idx < 65536) {
    const int j = idx - 49152, n = j >> 7, k = j & 127;
    WoT[j] = (_Float16)Wo[k * 128 + n];
  } else if (idx < 69632) {
    const int j = idx - 65536, s = j >> 7, c = j & 127;
    spH[j] = (s < 25) ? (_Float16)sp[s * 128 + c] : (_Float16)0.f;
  } else if (idx < 70016) {
    const int j = idx - 69632, t = j >> 7, n = j & 127;
    float a = 0.f;
    for (int c = 0; c < 128; ++c) a += te[t * 128 + c] * Wv[c * 128 + n];
    tv[j] = a;
  }
}

// ---------------------------------------------------------------------------
// Kernel A: QKV via MFMA (R13/R17 structure — measured ~45us, 0 conflicts).
// Depth-1 software pipeline on weight A-frags (neutral but not harmful).
// ---------------------------------------------------------------------------
__global__ __launch_bounds__(256, 3) void qkv_mfma(
    const float* __restrict__ values, const _Float16* __restrict__ WT,
    const float* __restrict__ temp_emb, const float* __restrict__ spatial_emb,
    const float* __restrict__ tv,
    _Float16* __restrict__ Qh, _Float16* __restrict__ Kh, _Float16* __restrict__ Vh)
{
  __shared__ __align__(16) _Float16 kin_s[64][140];
  const int tid = threadIdx.x;
  const int tok0 = blockIdx.x * 64;
  const int t = (tok0 >> 14) % T_;

  for (int i = tid; i < 64 * 32; i += 256) {
    const int tk = i >> 5, cg = i & 31;
    const float4 v = *(const float4*)&values[(size_t)(tok0 + tk) * C_ + cg * 4];
    const float4 e = *(const float4*)&temp_emb[t * C_ + cg * 4];
    f16x4 kv;
    kv[0] = (_Float16)(v.x + e.x); kv[1] = (_Float16)(v.y + e.y);
    kv[2] = (_Float16)(v.z + e.z); kv[3] = (_Float16)(v.w + e.w);
    *(f16x4*)&kin_s[tk][cg * 4] = kv;
  }

  const int l = tid & 63, w = tid >> 6, l15 = l & 15, g = l >> 4;
  const _Float16* Wbase = WT + (size_t)(w * 96) * 128;

  f16x4 acur[6], anxt[6];
#pragma unroll
  for (int j = 0; j < 6; ++j)
    acur[j] = *(const f16x4*)&Wbase[(size_t)(j * 16 + l15) * 128 + 4 * g];

  __syncthreads();

  f32x4 acc[6][4];
#pragma unroll
  for (int j = 0; j < 6; ++j)
#pragma unroll
    for (int tt = 0; tt < 4; ++tt) acc[j][tt] = (f32x4){0.f, 0.f, 0.f, 0.f};

#pragma unroll
  for (int kc = 0; kc < 8; ++kc) {
    if (kc < 7) {
      const int kon = (kc + 1) * 16 + 4 * g;
#pragma unroll
      for (int j = 0; j < 6; ++j)
        anxt[j] = *(const f16x4*)&Wbase[(size_t)(j * 16 + l15) * 128 + kon];
    }
    const int ko = kc * 16 + 4 * g;
    f16x4 bfr[4];
#pragma unroll
    for (int tt = 0; tt < 4; ++tt)
      bfr[tt] = *(const f16x4*)&kin_s[tt * 16 + l15][ko];
#pragma unroll
    for (int j = 0; j < 6; ++j)
#pragma unroll
      for (int tt = 0; tt < 4; ++tt)
        acc[j][tt] = mfma16(acur[j], bfr[tt], acc[j][tt]);
#pragma unroll
    for (int j = 0; j < 6; ++j) acur[j] = anxt[j];
  }

  constexpr float CSC = 0.25f * 1.44269504088896f;
#pragma unroll
  for (int j = 0; j < 6; ++j) {
    const int ntile = w * 6 + j;
    const int ch0 = (ntile & 7) * 16 + 4 * g;
#pragma unroll
    for (int tt = 0; tt < 4; ++tt) {
      const int tok = tok0 + tt * 16 + l15;
      const size_t o = (size_t)tok * CK_ + ch0;
      f16x4 r;
      if (ntile < 8) {
        const int x = tok & 127, y = (tok >> 7) & 127;
        const int cy = min(max(y, RY_), H_ - 1 - RY_);
        const int cx = min(max(x, RX_), W_ - 1 - RX_);
        const int qsp = (y - cy + RY_) * PW_ + (x - cx + RX_);
        const float4 e = *(const float4*)&spatial_emb[qsp * CK_ + ch0];
        r[0] = (_Float16)((acc[j][tt][0] + e.x) * CSC);
        r[1] = (_Float16)((acc[j][tt][1] + e.y) * CSC);
        r[2] = (_Float16)((acc[j][tt][2] + e.z) * CSC);
        r[3] = (_Float16)((acc[j][tt][3] + e.w) * CSC);
        *(f16x4*)&Qh[o] = r;
      } else if (ntile < 16) {
        r[0] = (_Float16)acc[j][tt][0]; r[1] = (_Float16)acc[j][tt][1];
        r[2] = (_Float16)acc[j][tt][2]; r[3] = (_Float16)acc[j][tt][3];
        *(f16x4*)&Kh[o] = r;
      } else {
        const float4 tve = *(const float4*)&tv[t * 128 + ch0];
        r[0] = (_Float16)(acc[j][tt][0] - tve.x);
        r[1] = (_Float16)(acc[j][tt][1] - tve.y);
        r[2] = (_Float16)(acc[j][tt][2] - tve.z);
        r[3] = (_Float16)(acc[j][tt][3] - tve.w);
        *(f16x4*)&Vh[o] = r;
      }
    }
  }
}

// ---------------------------------------------------------------------------
// Kernel B: MFMA attention — exact R15/R17 config (best measured: 94.7us).
// K_s stride 40, V_s stride 44, qe table [h][q][26] (odd word stride),
// bijective XCD swizzle, async reg prefetch, packed f16 softmax with mask
// folded into qe slot 25, s_setprio around the MFMA-dense region.
// ---------------------------------------------------------------------------
__global__ __launch_bounds__(256) void attn_mfma(
    const _Float16* __restrict__ Q, const _Float16* __restrict__ K,
    const _Float16* __restrict__ V, const _Float16* __restrict__ spH,
    _Float16* __restrict__ ck)
{
  __shared__ __align__(16) _Float16 K_s[192 * 40];
  __shared__ __align__(16) _Float16 V_s[192 * 44];
  __shared__ __align__(8)  _Float16 qe_s[2 * 64 * 26];  // [h][q][26]; slot25=-30000
  __shared__ float l_s[4][2][16];

  const int tid = threadIdx.x;
  const int bid0 = blockIdx.x;
  const int bid = (bid0 & 7) * 768 + (bid0 >> 3);   // bijective: 8a+b -> 768b+a
  const int hq = bid & 3;                 // head quarter: channels hq*32..+31
  const int tile = bid >> 2;
  const int tx = tile & 15, ty = (tile >> 4) & 15, img = tile >> 8;
  const int b = img / 3;
  const int y0 = ty * 8, x0 = tx * 8;
  const int rowbase = max(y0, 2) - 2;
  const int colbase = max(x0, 2) - 2;
  const int tokbase = img * 16384 + y0 * 128 + x0;
  const int chb = hq * 32;

  const int l = tid & 63, wv = tid >> 6, l15 = l & 15, g = l >> 4;
  const int q_glob = wv * 16 + l15;
  const int qy = 2 * wv + (l15 >> 3), qx = l15 & 7;
  const int y = y0 + qy, x = x0 + qx;
  const int tok = tokbase + qy * 128 + qx;
  const int cy = min(max(y, 2), 125), cx = min(max(x, 2), 125);
  const int myryc = cy - rowbase;
  const int rxc = cx - colbase;
  const int dxpbase = 4 * g - rxc + 2;

  const int rycA = min(max(y0 + 2 * wv,     2), 125) - rowbase;
  const int rycB = min(max(y0 + 2 * wv + 1, 2), 125) - rowbase;
  const int rymin = min(min(rycA, rycB) - 2, 6);

  // hoisted per-lane x-validity (fixed for whole kernel)
  bool vx[4];
#pragma unroll
  for (int i = 0; i < 4; ++i) vx[i] = (unsigned)(dxpbase + i) <= 4u;

  // ---- hoisted staging offsets (fixed across frames) ----
  int poff[6], ldoffK[6], ldoffV[6];
#pragma unroll
  for (int it = 0; it < 6; ++it) {
    const int idx = tid + it * 256;
    const int row = idx >> 3, cg = idx & 7;
    const int ny = min(rowbase + (row >> 4), 127);
    const int nx = min(colbase + (row & 15), 127);
    poff[it] = (ny * 128 + nx) * CK_ + chb + cg * 4;
    ldoffK[it] = row * 40 + cg * 4;
    ldoffV[it] = row * 44 + cg * 4;
  }
  const size_t imgstep = (size_t)16384 * CK_;
  const _Float16* Kp = K + (size_t)(b * 3) * imgstep;
  const _Float16* Vp = V + (size_t)(b * 3) * imgstep;

  // ---- prefetch frame 0 (in flight during qfrag/qe setup) ----
  f16x4 kpre[6], vpre[6];
#pragma unroll
  for (int it = 0; it < 6; ++it) {
    kpre[it] = *(const f16x4*)&Kp[poff[it]];
    vpre[it] = *(const f16x4*)&Vp[poff[it]];
  }

  // Q fragments (pre-scaled, spatial emb folded by qkv kernel)
  f16x4 qfrag[2];
#pragma unroll
  for (int h = 0; h < 2; ++h)
    qfrag[h] = *(const f16x4*)&Q[(size_t)tok * CK_ + chb + h * 16 + 4 * g];

  // qe[h][q][s] = Qs . emb_s via MFMA -> per-wave-private f16 table.
#pragma unroll
  for (int h = 0; h < 2; ++h) {
    const int qrow = (h * 64 + q_glob) * 26;
#pragma unroll
    for (int mt = 0; mt < 2; ++mt) {
      const f16x4 a = *(const f16x4*)&spH[(size_t)(mt * 16 + l15) * 128 + chb + h * 16 + 4 * g];
      f32x4 c = {0.f, 0.f, 0.f, 0.f};
      c = mfma16(a, qfrag[h], c);
      const int s0w = mt * 16 + 4 * g;       // s of c[0]
      if (mt == 0 || g < 2) {                // s0w..s0w+3 <= 23: full f16x4
        U32H2 p01, p23;
        p01.h = pkrtz(c[0], c[1]);
        p23.h = pkrtz(c[2], c[3]);
        *(unsigned*)&qe_s[qrow + s0w]     = p01.u;
        *(unsigned*)&qe_s[qrow + s0w + 2] = p23.u;
      } else if (g == 2) {                   // s = 24..27: only s=24 is real
        qe_s[qrow + 24] = (_Float16)c[0];
      }                                       // g == 3: s = 28..31, all dead
    }
  }
  // mask slot (after table writes; same-wave ordering)
  if (g == 0) {
    qe_s[(0 * 64 + q_glob) * 26 + 25] = (_Float16)(-30000.0f);
    qe_s[(1 * 64 + q_glob) * 26 + 25] = (_Float16)(-30000.0f);
  }

  f32x4 o_acc[2];
  float l_acc[2];
#pragma unroll
  for (int h = 0; h < 2; ++h) { o_acc[h] = (f32x4){0.f, 0.f, 0.f, 0.f}; l_acc[h] = 0.f; }

  const f16x2 ones2 = {(_Float16)1.f, (_Float16)1.f};

#pragma unroll
  for (int t = 0; t < 3; ++t) {
    if (t) __syncthreads();           // prev-frame reads done before restage
#pragma unroll
    for (int it = 0; it < 6; ++it) {
      *(f16x4*)&K_s[ldoffK[it]] = kpre[it];
      *(f16x4*)&V_s[ldoffV[it]] = vpre[it];
    }
    __syncthreads();                  // staging visible
    if (t < 2) {                      // issue next frame's loads before compute
      const _Float16* Kt = Kp + (size_t)(t + 1) * imgstep;
      const _Float16* Vt = Vp + (size_t)(t + 1) * imgstep;
#pragma unroll
      for (int it = 0; it < 6; ++it) {
        kpre[it] = *(const f16x4*)&Kt[poff[it]];
        vpre[it] = *(const f16x4*)&Vt[poff[it]];
      }
    }

    __builtin_amdgcn_s_setprio(1);
    f16x4 wfr[2][6];
#pragma unroll
    for (int jj = 0; jj < 6; ++jj) {
      const int nt = rymin + jj;
      // both head MFMAs first
      f32x4 c0 = {0.f, 0.f, 0.f, 0.f}, c1 = {0.f, 0.f, 0.f, 0.f};
      {
        const f16x4 a0 = *(const f16x4*)&K_s[(nt * 16 + l15) * 40 + 4 * g];
        const f16x4 a1 = *(const f16x4*)&K_s[(nt * 16 + l15) * 40 + 16 + 4 * g];
        c0 = mfma16(a0, qfrag[0], c0);
        c1 = mfma16(a1, qfrag[1], c1);
      }
      // shared index math (identical for both heads)
      const int dyp = nt - myryc + 2;
      const bool vy = (unsigned)dyp <= 4u;
      const int s0 = dyp * 5 + dxpbase;
      int si[4];
#pragma unroll
      for (int i = 0; i < 4; ++i) si[i] = (vy && vx[i]) ? s0 + i : 25;
#pragma unroll
      for (int h = 0; h < 2; ++h) {
        const f32x4 c = h ? c1 : c0;
        const int qb = (h * 64 + q_glob) * 26;
        // combine qe pairs (u16 reads -> packed)
        U32H2 q01, q23;
        q01.u = (unsigned)(unsigned short)__builtin_bit_cast(short, qe_s[qb + si[0]])
              | ((unsigned)(unsigned short)__builtin_bit_cast(short, qe_s[qb + si[1]]) << 16);
        q23.u = (unsigned)(unsigned short)__builtin_bit_cast(short, qe_s[qb + si[2]])
              | ((unsigned)(unsigned short)__builtin_bit_cast(short, qe_s[qb + si[3]]) << 16);
        const f16x2 s01 = pkrtz(c[0], c[1]) + q01.h;
        const f16x2 s23 = pkrtz(c[2], c[3]) + q23.h;
        U32H2 p01, p23;
        p01.u = pk_exp2(s01);
        p23.u = pk_exp2(s23);
        l_acc[h] = __builtin_amdgcn_fdot2(p01.h, ones2, l_acc[h], false);
        l_acc[h] = __builtin_amdgcn_fdot2(p23.h, ones2, l_acc[h], false);
        union { unsigned u[2]; f16x4 v; } wu;
        wu.u[0] = p01.u; wu.u[1] = p23.u;
        wfr[h][jj] = wu.v;
      }
    }

    // PV: o = w . V  (w C-frag reused as A-frag; V row-major B-frags)
#pragma unroll
    for (int h = 0; h < 2; ++h) {
#pragma unroll
      for (int jj = 0; jj < 6; ++jj) {
        const int nt = rymin + jj;
        f16x4 bv;
#pragma unroll
        for (int i = 0; i < 4; ++i)
          bv[i] = V_s[(nt * 16 + 4 * g + i) * 44 + h * 16 + l15];
        o_acc[h] = mfma16(wfr[h][jj], bv, o_acc[h]);
      }
    }
    __builtin_amdgcn_s_setprio(0);
  }

  // normalize: l lives per (q=l15); o lives per (q=4g+i, ch=l15) -> via LDS
#pragma unroll
  for (int h = 0; h < 2; ++h) {
    float lt = l_acc[h];
    lt += __shfl_xor(lt, 16);
    lt += __shfl_xor(lt, 32);
    if (l < 16) l_s[wv][h][l15] = 1.f / lt;
  }
#pragma unroll
  for (int h = 0; h < 2; ++h) {
#pragma unroll
    for (int i = 0; i < 4; ++i) {
      const int q = 4 * g + i;
      const float inv = l_s[wv][h][q];
      const int qtok = tokbase + (2 * wv + (q >> 3)) * 128 + (q & 7);
      ck[(size_t)qtok * CK_ + chb + h * 16 + l15] = (_Float16)(o_acc[h][i] * inv);
    }
  }
}

// ---------------------------------------------------------------------------
// Kernel C: out = ck @ Wo via MFMA. Block = 128 tokens; wave = 2 N-tiles x 8
// token-tiles. ck_s stride 152 (bank spread ~2/bank).
// ---------------------------------------------------------------------------
__global__ __launch_bounds__(256) void out_mfma(
    const _Float16* __restrict__ ck, const _Float16* __restrict__ WoT,
    float* __restrict__ out)
{
  __shared__ __align__(16) _Float16 ck_s[128][152];
  const int tid = threadIdx.x;
  const int tok0 = blockIdx.x * 128;

  for (int i = tid; i < 128 * 16; i += 256) {
    const int tk = i >> 4, cg = i & 15;
    *(f16x8*)&ck_s[tk][cg * 8] = *(const f16x8*)&ck[(size_t)(tok0 + tk) * C_ + cg * 8];
  }
  __syncthreads();

  const int l = tid & 63, w = tid >> 6, l15 = l & 15, g = l >> 4;

  f32x4 acc[2][8];
#pragma unroll
  for (int j = 0; j < 2; ++j)
#pragma unroll
    for (int tt = 0; tt < 8; ++tt) acc[j][tt] = (f32x4){0.f, 0.f, 0.f, 0.f};

  for (int kc = 0; kc < 8; ++kc) {
    const int ko = kc * 16 + 4 * g;
    f16x4 bfr[8];
#pragma unroll
    for (int tt = 0; tt < 8; ++tt)
      bfr[tt] = *(const f16x4*)&ck_s[tt * 16 + l15][ko];
#pragma unroll
    for (int j = 0; j < 2; ++j) {
      const f16x4 a = *(const f16x4*)&WoT[(size_t)((w * 2 + j) * 16 + l15) * 128 + ko];
#pragma unroll
      for (int tt = 0; tt < 8; ++tt)
        acc[j][tt] = mfma16(a, bfr[tt], acc[j][tt]);
    }
  }

#pragma unroll
  for (int j = 0; j < 2; ++j) {
    const int ch0 = (w * 2 + j) * 16 + 4 * g;
#pragma unroll
    for (int tt = 0; tt < 8; ++tt) {
      const int tok = tok0 + tt * 16 + l15;
      float4 ov;
      ov.x = acc[j][tt][0]; ov.y = acc[j][tt][1];
      ov.z = acc[j][tt][2]; ov.w = acc[j][tt][3];
      *(float4*)&out[(size_t)tok * C_ + ch0] = ov;
    }
  }
}

// ---------------------------------------------------------------------------
extern "C" void kernel_launch(void* const* d_in, const int* in_sizes, int n_in,
                              void* d_out, int out_size, void* d_ws, size_t ws_size,
                              hipStream_t stream) {
    const float* values      = (const float*)d_in[0];
    const float* Wq          = (const float*)d_in[1];
    const float* Wk          = (const float*)d_in[2];
    const float* Wv          = (const float*)d_in[3];
    const float* Wo          = (const float*)d_in[4];
    const float* temp_emb    = (const float*)d_in[5];
    const float* spatial_emb = (const float*)d_in[6];
    float* out = (float*)d_out;

    const size_t NC = (size_t)NTOK * CK_;
    _Float16* Qh  = (_Float16*)d_ws;
    _Float16* Kh  = Qh  + NC;
    _Float16* Vh  = Kh  + NC;
    _Float16* ckh = Vh  + NC;
    _Float16* WT  = ckh + NC;          // [384][128]
    _Float16* WoT = WT  + 49152;       // [128][128]
    _Float16* spH = WoT + 16384;       // [32][128]
    float*    tv  = (float*)(spH + 4096);  // [3][128]

    prep<<<274, 256, 0, stream>>>(Wq, Wk, Wv, Wo, spatial_emb, temp_emb,
                                  WT, WoT, spH, tv);
    qkv_mfma<<<NTOK / 64, 256, 0, stream>>>(values, WT, temp_emb, spatial_emb,
                                            tv, Qh, Kh, Vh);
    attn_mfma<<<6144, 256, 0, stream>>>(Qh, Kh, Vh, spH, ckh);
    out_mfma<<<NTOK / 128, 256, 0, stream>>>(ckh, WoT, out);
}

// Round 22
// 163.655 us; speedup vs baseline: 1.2960x; 1.0380x over previous
//
#include <hip/hip_runtime.h>
#include <hip/hip_fp16.h>
#include <math.h>

// Problem constants (fixed by the reference).
constexpr int B_ = 2, T_ = 3, H_ = 128, W_ = 128, C_ = 128;
constexpr int HEADS_ = 8, D_ = 16, CK_ = 128;
constexpr int RY_ = 2, RX_ = 2, PH_ = 5, PW_ = 5, S_ = 25;
constexpr int NTOK = B_ * T_ * H_ * W_;   // 98304 tokens

typedef float     f32x4 __attribute__((ext_vector_type(4)));
typedef _Float16  f16x2 __attribute__((ext_vector_type(2)));
typedef _Float16  f16x4 __attribute__((ext_vector_type(4)));
typedef _Float16  f16x8 __attribute__((ext_vector_type(8)));

static __device__ __forceinline__ f32x4 mfma16(f16x4 a, f16x4 b, f32x4 c) {
#if __has_builtin(__builtin_amdgcn_mfma_f32_16x16x16f16)
  return __builtin_amdgcn_mfma_f32_16x16x16f16(a, b, c, 0, 0, 0);
#else
  asm volatile("v_mfma_f32_16x16x16_f16 %0, %1, %2, %0" : "+v"(c) : "v"(a), "v"(b));
  return c;
#endif
}

union U32H2 { unsigned u; f16x2 h; __half2 hh; };

// v_cvt_pkrtz_f16_f32 returns __fp16x2; bit-cast to our f16x2 (same bits).
static __device__ __forceinline__ f16x2 pkrtz(float a, float b) {
  return __builtin_bit_cast(f16x2, __builtin_amdgcn_cvt_pkrtz(a, b));
}

static __device__ __forceinline__ unsigned pk_exp2(f16x2 x) {
  U32H2 in, out;
  in.h = x;
  out.hh = h2exp2(in.hh);      // 2x v_exp_f16 (2^x per half)
  return out.u;
}

// ---------------------------------------------------------------------------
// Kernel P: pack weights fp16 transposed; spatial_emb fp16 padded [32][128];
// tv[t][n] = temp_emb[t] @ Wv (rank-1 correction so V shares the kin input).
// WT = [Wq^T; Wk^T; Wv^T] stacked as [384 n][128 k].
// ---------------------------------------------------------------------------
__global__ __launch_bounds__(256) void prep(
    const float* __restrict__ Wq, const float* __restrict__ Wk,
    const float* __restrict__ Wv, const float* __restrict__ Wo,
    const float* __restrict__ sp, const float* __restrict__ te,
    _Float16* __restrict__ WT, _Float16* __restrict__ WoT,
    _Float16* __restrict__ spH, float* __restrict__ tv)
{
  const int idx = blockIdx.x * 256 + threadIdx.x;
  if (idx < 49152) {
    const int m = idx >> 14, j = idx & 16383, n = j >> 7, k = j & 127;
    const float* Wm = (m == 0) ? Wq : ((m == 1) ? Wk : Wv);
    WT[idx] = (_Float16)Wm[k * 128 + n];
  } else if (idx < 65536) {
    const int j = idx - 49152, n = j >> 7, k = j & 127;
    WoT[j] = (_Float16)Wo[k * 128 + n];
  } else if (idx < 69632) {
    const int j = idx - 65536, s = j >> 7, c = j & 127;
    spH[j] = (s < 25) ? (_Float16)sp[s * 128 + c] : (_Float16)0.f;
  } else if (idx < 70016) {
    const int j = idx - 69632, t = j >> 7, n = j & 127;
    float a = 0.f;
    for (int c = 0; c < 128; ++c) a += te[t * 128 + c] * Wv[c * 128 + n];
    tv[j] = a;
  }
}

// ---------------------------------------------------------------------------
// Kernel A: QKV via MFMA (R13/R17 structure — measured ~45us, 0 conflicts).
// ---------------------------------------------------------------------------
__global__ __launch_bounds__(256, 3) void qkv_mfma(
    const float* __restrict__ values, const _Float16* __restrict__ WT,
    const float* __restrict__ temp_emb, const float* __restrict__ spatial_emb,
    const float* __restrict__ tv,
    _Float16* __restrict__ Qh, _Float16* __restrict__ Kh, _Float16* __restrict__ Vh)
{
  __shared__ __align__(16) _Float16 kin_s[64][140];
  const int tid = threadIdx.x;
  const int tok0 = blockIdx.x * 64;
  const int t = (tok0 >> 14) % T_;

  for (int i = tid; i < 64 * 32; i += 256) {
    const int tk = i >> 5, cg = i & 31;
    const float4 v = *(const float4*)&values[(size_t)(tok0 + tk) * C_ + cg * 4];
    const float4 e = *(const float4*)&temp_emb[t * C_ + cg * 4];
    f16x4 kv;
    kv[0] = (_Float16)(v.x + e.x); kv[1] = (_Float16)(v.y + e.y);
    kv[2] = (_Float16)(v.z + e.z); kv[3] = (_Float16)(v.w + e.w);
    *(f16x4*)&kin_s[tk][cg * 4] = kv;
  }

  const int l = tid & 63, w = tid >> 6, l15 = l & 15, g = l >> 4;
  const _Float16* Wbase = WT + (size_t)(w * 96) * 128;

  f16x4 acur[6], anxt[6];
#pragma unroll
  for (int j = 0; j < 6; ++j)
    acur[j] = *(const f16x4*)&Wbase[(size_t)(j * 16 + l15) * 128 + 4 * g];

  __syncthreads();

  f32x4 acc[6][4];
#pragma unroll
  for (int j = 0; j < 6; ++j)
#pragma unroll
    for (int tt = 0; tt < 4; ++tt) acc[j][tt] = (f32x4){0.f, 0.f, 0.f, 0.f};

#pragma unroll
  for (int kc = 0; kc < 8; ++kc) {
    if (kc < 7) {
      const int kon = (kc + 1) * 16 + 4 * g;
#pragma unroll
      for (int j = 0; j < 6; ++j)
        anxt[j] = *(const f16x4*)&Wbase[(size_t)(j * 16 + l15) * 128 + kon];
    }
    const int ko = kc * 16 + 4 * g;
    f16x4 bfr[4];
#pragma unroll
    for (int tt = 0; tt < 4; ++tt)
      bfr[tt] = *(const f16x4*)&kin_s[tt * 16 + l15][ko];
#pragma unroll
    for (int j = 0; j < 6; ++j)
#pragma unroll
      for (int tt = 0; tt < 4; ++tt)
        acc[j][tt] = mfma16(acur[j], bfr[tt], acc[j][tt]);
#pragma unroll
    for (int j = 0; j < 6; ++j) acur[j] = anxt[j];
  }

  constexpr float CSC = 0.25f * 1.44269504088896f;
#pragma unroll
  for (int j = 0; j < 6; ++j) {
    const int ntile = w * 6 + j;
    const int ch0 = (ntile & 7) * 16 + 4 * g;
#pragma unroll
    for (int tt = 0; tt < 4; ++tt) {
      const int tok = tok0 + tt * 16 + l15;
      const size_t o = (size_t)tok * CK_ + ch0;
      f16x4 r;
      if (ntile < 8) {
        const int x = tok & 127, y = (tok >> 7) & 127;
        const int cy = min(max(y, RY_), H_ - 1 - RY_);
        const int cx = min(max(x, RX_), W_ - 1 - RX_);
        const int qsp = (y - cy + RY_) * PW_ + (x - cx + RX_);
        const float4 e = *(const float4*)&spatial_emb[qsp * CK_ + ch0];
        r[0] = (_Float16)((acc[j][tt][0] + e.x) * CSC);
        r[1] = (_Float16)((acc[j][tt][1] + e.y) * CSC);
        r[2] = (_Float16)((acc[j][tt][2] + e.z) * CSC);
        r[3] = (_Float16)((acc[j][tt][3] + e.w) * CSC);
        *(f16x4*)&Qh[o] = r;
      } else if (ntile < 16) {
        r[0] = (_Float16)acc[j][tt][0]; r[1] = (_Float16)acc[j][tt][1];
        r[2] = (_Float16)acc[j][tt][2]; r[3] = (_Float16)acc[j][tt][3];
        *(f16x4*)&Kh[o] = r;
      } else {
        const float4 tve = *(const float4*)&tv[t * 128 + ch0];
        r[0] = (_Float16)(acc[j][tt][0] - tve.x);
        r[1] = (_Float16)(acc[j][tt][1] - tve.y);
        r[2] = (_Float16)(acc[j][tt][2] - tve.z);
        r[3] = (_Float16)(acc[j][tt][3] - tve.w);
        *(f16x4*)&Vh[o] = r;
      }
    }
  }
}

// ---------------------------------------------------------------------------
// Kernel B: MFMA attention v11 = R17 + qe-gather HOISTED out of the frame
// loop. si[] depends only on geometry (dyp, dxpbase), never on t — R17 was
// re-gathering the identical 288 u16 bias values every frame. Now gathered
// once into 24 registers (qe01/qe23[2][6], statically indexed); frame loop
// uses them directly. Saves ~192 scalar ds_read_u16 + ~130 VALU per wave.
// ---------------------------------------------------------------------------
__global__ __launch_bounds__(256) void attn_mfma(
    const _Float16* __restrict__ Q, const _Float16* __restrict__ K,
    const _Float16* __restrict__ V, const _Float16* __restrict__ spH,
    _Float16* __restrict__ ck)
{
  __shared__ __align__(16) _Float16 K_s[192 * 40];
  __shared__ __align__(16) _Float16 V_s[192 * 44];
  __shared__ __align__(8)  _Float16 qe_s[2 * 64 * 26];  // [h][q][26]; slot25=-30000
  __shared__ float l_s[4][2][16];

  const int tid = threadIdx.x;
  const int bid0 = blockIdx.x;
  const int bid = (bid0 & 7) * 768 + (bid0 >> 3);   // bijective: 8a+b -> 768b+a
  const int hq = bid & 3;                 // head quarter: channels hq*32..+31
  const int tile = bid >> 2;
  const int tx = tile & 15, ty = (tile >> 4) & 15, img = tile >> 8;
  const int b = img / 3;
  const int y0 = ty * 8, x0 = tx * 8;
  const int rowbase = max(y0, 2) - 2;
  const int colbase = max(x0, 2) - 2;
  const int tokbase = img * 16384 + y0 * 128 + x0;
  const int chb = hq * 32;

  const int l = tid & 63, wv = tid >> 6, l15 = l & 15, g = l >> 4;
  const int q_glob = wv * 16 + l15;
  const int qy = 2 * wv + (l15 >> 3), qx = l15 & 7;
  const int y = y0 + qy, x = x0 + qx;
  const int tok = tokbase + qy * 128 + qx;
  const int cy = min(max(y, 2), 125), cx = min(max(x, 2), 125);
  const int myryc = cy - rowbase;
  const int rxc = cx - colbase;
  const int dxpbase = 4 * g - rxc + 2;

  const int rycA = min(max(y0 + 2 * wv,     2), 125) - rowbase;
  const int rycB = min(max(y0 + 2 * wv + 1, 2), 125) - rowbase;
  const int rymin = min(min(rycA, rycB) - 2, 6);

  // hoisted per-lane x-validity (fixed for whole kernel)
  bool vx[4];
#pragma unroll
  for (int i = 0; i < 4; ++i) vx[i] = (unsigned)(dxpbase + i) <= 4u;

  // ---- hoisted staging offsets (fixed across frames) ----
  int poff[6], ldoffK[6], ldoffV[6];
#pragma unroll
  for (int it = 0; it < 6; ++it) {
    const int idx = tid + it * 256;
    const int row = idx >> 3, cg = idx & 7;
    const int ny = min(rowbase + (row >> 4), 127);
    const int nx = min(colbase + (row & 15), 127);
    poff[it] = (ny * 128 + nx) * CK_ + chb + cg * 4;
    ldoffK[it] = row * 40 + cg * 4;
    ldoffV[it] = row * 44 + cg * 4;
  }
  const size_t imgstep = (size_t)16384 * CK_;
  const _Float16* Kp = K + (size_t)(b * 3) * imgstep;
  const _Float16* Vp = V + (size_t)(b * 3) * imgstep;

  // ---- prefetch frame 0 (in flight during qfrag/qe setup) ----
  f16x4 kpre[6], vpre[6];
#pragma unroll
  for (int it = 0; it < 6; ++it) {
    kpre[it] = *(const f16x4*)&Kp[poff[it]];
    vpre[it] = *(const f16x4*)&Vp[poff[it]];
  }

  // Q fragments (pre-scaled, spatial emb folded by qkv kernel)
  f16x4 qfrag[2];
#pragma unroll
  for (int h = 0; h < 2; ++h)
    qfrag[h] = *(const f16x4*)&Q[(size_t)tok * CK_ + chb + h * 16 + 4 * g];

  // qe[h][q][s] = Qs . emb_s via MFMA -> per-wave-private f16 table.
#pragma unroll
  for (int h = 0; h < 2; ++h) {
    const int qrow = (h * 64 + q_glob) * 26;
#pragma unroll
    for (int mt = 0; mt < 2; ++mt) {
      const f16x4 a = *(const f16x4*)&spH[(size_t)(mt * 16 + l15) * 128 + chb + h * 16 + 4 * g];
      f32x4 c = {0.f, 0.f, 0.f, 0.f};
      c = mfma16(a, qfrag[h], c);
      const int s0w = mt * 16 + 4 * g;       // s of c[0]
      if (mt == 0 || g < 2) {                // s0w..s0w+3 <= 23: full f16x4
        U32H2 p01, p23;
        p01.h = pkrtz(c[0], c[1]);
        p23.h = pkrtz(c[2], c[3]);
        *(unsigned*)&qe_s[qrow + s0w]     = p01.u;
        *(unsigned*)&qe_s[qrow + s0w + 2] = p23.u;
      } else if (g == 2) {                   // s = 24..27: only s=24 is real
        qe_s[qrow + 24] = (_Float16)c[0];
      }                                       // g == 3: s = 28..31, all dead
    }
  }
  // mask slot (after table writes; same-wave ordering)
  if (g == 0) {
    qe_s[(0 * 64 + q_glob) * 26 + 25] = (_Float16)(-30000.0f);
    qe_s[(1 * 64 + q_glob) * 26 + 25] = (_Float16)(-30000.0f);
  }

  // ---- FRAME-INVARIANT qe gather, hoisted: 24 regs (2h x 6jj x 2 words) ----
  unsigned qe01[2][6], qe23[2][6];
#pragma unroll
  for (int jj = 0; jj < 6; ++jj) {
    const int nt = rymin + jj;
    const int dyp = nt - myryc + 2;
    const bool vy = (unsigned)dyp <= 4u;
    const int s0 = dyp * 5 + dxpbase;
    int si[4];
#pragma unroll
    for (int i = 0; i < 4; ++i) si[i] = (vy && vx[i]) ? s0 + i : 25;
#pragma unroll
    for (int h = 0; h < 2; ++h) {
      const int qb = (h * 64 + q_glob) * 26;
      qe01[h][jj] = (unsigned)(unsigned short)__builtin_bit_cast(short, qe_s[qb + si[0]])
                  | ((unsigned)(unsigned short)__builtin_bit_cast(short, qe_s[qb + si[1]]) << 16);
      qe23[h][jj] = (unsigned)(unsigned short)__builtin_bit_cast(short, qe_s[qb + si[2]])
                  | ((unsigned)(unsigned short)__builtin_bit_cast(short, qe_s[qb + si[3]]) << 16);
    }
  }

  f32x4 o_acc[2];
  float l_acc[2];
#pragma unroll
  for (int h = 0; h < 2; ++h) { o_acc[h] = (f32x4){0.f, 0.f, 0.f, 0.f}; l_acc[h] = 0.f; }

  const f16x2 ones2 = {(_Float16)1.f, (_Float16)1.f};

#pragma unroll
  for (int t = 0; t < 3; ++t) {
    if (t) __syncthreads();           // prev-frame reads done before restage
#pragma unroll
    for (int it = 0; it < 6; ++it) {
      *(f16x4*)&K_s[ldoffK[it]] = kpre[it];
      *(f16x4*)&V_s[ldoffV[it]] = vpre[it];
    }
    __syncthreads();                  // staging visible
    if (t < 2) {                      // issue next frame's loads before compute
      const _Float16* Kt = Kp + (size_t)(t + 1) * imgstep;
      const _Float16* Vt = Vp + (size_t)(t + 1) * imgstep;
#pragma unroll
      for (int it = 0; it < 6; ++it) {
        kpre[it] = *(const f16x4*)&Kt[poff[it]];
        vpre[it] = *(const f16x4*)&Vt[poff[it]];
      }
    }

    __builtin_amdgcn_s_setprio(1);
    f16x4 wfr[2][6];
#pragma unroll
    for (int jj = 0; jj < 6; ++jj) {
      const int nt = rymin + jj;
      // both head MFMAs first
      f32x4 c0 = {0.f, 0.f, 0.f, 0.f}, c1 = {0.f, 0.f, 0.f, 0.f};
      {
        const f16x4 a0 = *(const f16x4*)&K_s[(nt * 16 + l15) * 40 + 4 * g];
        const f16x4 a1 = *(const f16x4*)&K_s[(nt * 16 + l15) * 40 + 16 + 4 * g];
        c0 = mfma16(a0, qfrag[0], c0);
        c1 = mfma16(a1, qfrag[1], c1);
      }
#pragma unroll
      for (int h = 0; h < 2; ++h) {
        const f32x4 c = h ? c1 : c0;
        U32H2 q01, q23;
        q01.u = qe01[h][jj];
        q23.u = qe23[h][jj];
        const f16x2 s01 = pkrtz(c[0], c[1]) + q01.h;
        const f16x2 s23 = pkrtz(c[2], c[3]) + q23.h;
        U32H2 p01, p23;
        p01.u = pk_exp2(s01);
        p23.u = pk_exp2(s23);
        l_acc[h] = __builtin_amdgcn_fdot2(p01.h, ones2, l_acc[h], false);
        l_acc[h] = __builtin_amdgcn_fdot2(p23.h, ones2, l_acc[h], false);
        union { unsigned u[2]; f16x4 v; } wu;
        wu.u[0] = p01.u; wu.u[1] = p23.u;
        wfr[h][jj] = wu.v;
      }
    }

    // PV: o = w . V  (w C-frag reused as A-frag; V row-major B-frags)
#pragma unroll
    for (int h = 0; h < 2; ++h) {
#pragma unroll
      for (int jj = 0; jj < 6; ++jj) {
        const int nt = rymin + jj;
        f16x4 bv;
#pragma unroll
        for (int i = 0; i < 4; ++i)
          bv[i] = V_s[(nt * 16 + 4 * g + i) * 44 + h * 16 + l15];
        o_acc[h] = mfma16(wfr[h][jj], bv, o_acc[h]);
      }
    }
    __builtin_amdgcn_s_setprio(0);
  }

  // normalize: l lives per (q=l15); o lives per (q=4g+i, ch=l15) -> via LDS
#pragma unroll
  for (int h = 0; h < 2; ++h) {
    float lt = l_acc[h];
    lt += __shfl_xor(lt, 16);
    lt += __shfl_xor(lt, 32);
    if (l < 16) l_s[wv][h][l15] = 1.f / lt;
  }
#pragma unroll
  for (int h = 0; h < 2; ++h) {
#pragma unroll
    for (int i = 0; i < 4; ++i) {
      const int q = 4 * g + i;
      const float inv = l_s[wv][h][q];
      const int qtok = tokbase + (2 * wv + (q >> 3)) * 128 + (q & 7);
      ck[(size_t)qtok * CK_ + chb + h * 16 + l15] = (_Float16)(o_acc[h][i] * inv);
    }
  }
}

// ---------------------------------------------------------------------------
// Kernel C: out = ck @ Wo via MFMA. Block = 128 tokens; wave = 2 N-tiles x 8
// token-tiles. ck_s stride 152 (bank spread ~2/bank).
// ---------------------------------------------------------------------------
__global__ __launch_bounds__(256) void out_mfma(
    const _Float16* __restrict__ ck, const _Float16* __restrict__ WoT,
    float* __restrict__ out)
{
  __shared__ __align__(16) _Float16 ck_s[128][152];
  const int tid = threadIdx.x;
  const int tok0 = blockIdx.x * 128;

  for (int i = tid; i < 128 * 16; i += 256) {
    const int tk = i >> 4, cg = i & 15;
    *(f16x8*)&ck_s[tk][cg * 8] = *(const f16x8*)&ck[(size_t)(tok0 + tk) * C_ + cg * 8];
  }
  __syncthreads();

  const int l = tid & 63, w = tid >> 6, l15 = l & 15, g = l >> 4;

  f32x4 acc[2][8];
#pragma unroll
  for (int j = 0; j < 2; ++j)
#pragma unroll
    for (int tt = 0; tt < 8; ++tt) acc[j][tt] = (f32x4){0.f, 0.f, 0.f, 0.f};

  for (int kc = 0; kc < 8; ++kc) {
    const int ko = kc * 16 + 4 * g;
    f16x4 bfr[8];
#pragma unroll
    for (int tt = 0; tt < 8; ++tt)
      bfr[tt] = *(const f16x4*)&ck_s[tt * 16 + l15][ko];
#pragma unroll
    for (int j = 0; j < 2; ++j) {
      const f16x4 a = *(const f16x4*)&WoT[(size_t)((w * 2 + j) * 16 + l15) * 128 + ko];
#pragma unroll
      for (int tt = 0; tt < 8; ++tt)
        acc[j][tt] = mfma16(a, bfr[tt], acc[j][tt]);
    }
  }

#pragma unroll
  for (int j = 0; j < 2; ++j) {
    const int ch0 = (w * 2 + j) * 16 + 4 * g;
#pragma unroll
    for (int tt = 0; tt < 8; ++tt) {
      const int tok = tok0 + tt * 16 + l15;
      float4 ov;
      ov.x = acc[j][tt][0]; ov.y = acc[j][tt][1];
      ov.z = acc[j][tt][2]; ov.w = acc[j][tt][3];
      *(float4*)&out[(size_t)tok * C_ + ch0] = ov;
    }
  }
}

// ---------------------------------------------------------------------------
extern "C" void kernel_launch(void* const* d_in, const int* in_sizes, int n_in,
                              void* d_out, int out_size, void* d_ws, size_t ws_size,
                              hipStream_t stream) {
    const float* values      = (const float*)d_in[0];
    const float* Wq          = (const float*)d_in[1];
    const float* Wk          = (const float*)d_in[2];
    const float* Wv          = (const float*)d_in[3];
    const float* Wo          = (const float*)d_in[4];
    const float* temp_emb    = (const float*)d_in[5];
    const float* spatial_emb = (const float*)d_in[6];
    float* out = (float*)d_out;

    const size_t NC = (size_t)NTOK * CK_;
    _Float16* Qh  = (_Float16*)d_ws;
    _Float16* Kh  = Qh  + NC;
    _Float16* Vh  = Kh  + NC;
    _Float16* ckh = Vh  + NC;
    _Float16* WT  = ckh + NC;          // [384][128]
    _Float16* WoT = WT  + 49152;       // [128][128]
    _Float16* spH = WoT + 16384;       // [32][128]
    float*    tv  = (float*)(spH + 4096);  // [3][128]

    prep<<<274, 256, 0, stream>>>(Wq, Wk, Wv, Wo, spatial_emb, temp_emb,
                                  WT, WoT, spH, tv);
    qkv_mfma<<<NTOK / 64, 256, 0, stream>>>(values, WT, temp_emb, spatial_emb,
                                            tv, Qh, Kh, Vh);
    attn_mfma<<<6144, 256, 0, stream>>>(Qh, Kh, Vh, spH, ckh);
    out_mfma<<<NTOK / 128, 256, 0, stream>>>(ckh, WoT, out);
}

// Round 23
// 162.231 us; speedup vs baseline: 1.3074x; 1.0088x over previous
//
#include <hip/hip_runtime.h>
#include <hip/hip_fp16.h>
#include <math.h>

// Problem constants (fixed by the reference).
constexpr int B_ = 2, T_ = 3, H_ = 128, W_ = 128, C_ = 128;
constexpr int HEADS_ = 8, D_ = 16, CK_ = 128;
constexpr int RY_ = 2, RX_ = 2, PH_ = 5, PW_ = 5, S_ = 25;
constexpr int NTOK = B_ * T_ * H_ * W_;   // 98304 tokens

typedef float     f32x4 __attribute__((ext_vector_type(4)));
typedef _Float16  f16x2 __attribute__((ext_vector_type(2)));
typedef _Float16  f16x4 __attribute__((ext_vector_type(4)));
typedef _Float16  f16x8 __attribute__((ext_vector_type(8)));

static __device__ __forceinline__ f32x4 mfma16(f16x4 a, f16x4 b, f32x4 c) {
#if __has_builtin(__builtin_amdgcn_mfma_f32_16x16x16f16)
  return __builtin_amdgcn_mfma_f32_16x16x16f16(a, b, c, 0, 0, 0);
#else
  asm volatile("v_mfma_f32_16x16x16_f16 %0, %1, %2, %0" : "+v"(c) : "v"(a), "v"(b));
  return c;
#endif
}

union U32H2 { unsigned u; f16x2 h; __half2 hh; };

// v_cvt_pkrtz_f16_f32 returns __fp16x2; bit-cast to our f16x2 (same bits).
static __device__ __forceinline__ f16x2 pkrtz(float a, float b) {
  return __builtin_bit_cast(f16x2, __builtin_amdgcn_cvt_pkrtz(a, b));
}

static __device__ __forceinline__ unsigned pk_exp2(f16x2 x) {
  U32H2 in, out;
  in.h = x;
  out.hh = h2exp2(in.hh);      // 2x v_exp_f16 (2^x per half)
  return out.u;
}

// ---------------------------------------------------------------------------
// Kernel P: pack weights fp16 transposed; spatial_emb fp16 padded [32][128];
// tv[t][n] = temp_emb[t] @ Wv (rank-1 correction so V shares the kin input).
// WT = [Wq^T; Wk^T; Wv^T] stacked as [384 n][128 k].
// ---------------------------------------------------------------------------
__global__ __launch_bounds__(256) void prep(
    const float* __restrict__ Wq, const float* __restrict__ Wk,
    const float* __restrict__ Wv, const float* __restrict__ Wo,
    const float* __restrict__ sp, const float* __restrict__ te,
    _Float16* __restrict__ WT, _Float16* __restrict__ WoT,
    _Float16* __restrict__ spH, float* __restrict__ tv)
{
  const int idx = blockIdx.x * 256 + threadIdx.x;
  if (idx < 49152) {
    const int m = idx >> 14, j = idx & 16383, n = j >> 7, k = j & 127;
    const float* Wm = (m == 0) ? Wq : ((m == 1) ? Wk : Wv);
    WT[idx] = (_Float16)Wm[k * 128 + n];
  } else if (idx < 65536) {
    const int j = idx - 49152, n = j >> 7, k = j & 127;
    WoT[j] = (_Float16)Wo[k * 128 + n];
  } else if (idx < 69632) {
    const int j = idx - 65536, s = j >> 7, c = j & 127;
    spH[j] = (s < 25) ? (_Float16)sp[s * 128 + c] : (_Float16)0.f;
  } else if (idx < 70016) {
    const int j = idx - 69632, t = j >> 7, n = j & 127;
    float a = 0.f;
    for (int c = 0; c < 128; ++c) a += te[t * 128 + c] * Wv[c * 128 + n];
    tv[j] = a;
  }
}

// ---------------------------------------------------------------------------
// Kernel A: QKV via MFMA v6: occupancy via WIDER blocks. 512 thr = 8 waves,
// 64 tokens; wave = 3 N-tiles x 4 token-tiles (acc[3][4] = 48 regs, ~100
// total). LDS 17.9KB; lb(512,4) caps VGPR at 128 (> need -> no squeeze) ->
// 2 blocks/CU = 16 waves/CU (R13 had 12). A-frag reuse unchanged (4x).
// Tripwire: qkv WRITE_SIZE must stay ~75MB (no spill).
// ---------------------------------------------------------------------------
__global__ __launch_bounds__(512, 4) void qkv_mfma(
    const float* __restrict__ values, const _Float16* __restrict__ WT,
    const float* __restrict__ temp_emb, const float* __restrict__ spatial_emb,
    const float* __restrict__ tv,
    _Float16* __restrict__ Qh, _Float16* __restrict__ Kh, _Float16* __restrict__ Vh)
{
  __shared__ __align__(16) _Float16 kin_s[64][140];
  const int tid = threadIdx.x;
  const int tok0 = blockIdx.x * 64;
  const int t = (tok0 >> 14) % T_;

  for (int i = tid; i < 64 * 32; i += 512) {
    const int tk = i >> 5, cg = i & 31;
    const float4 v = *(const float4*)&values[(size_t)(tok0 + tk) * C_ + cg * 4];
    const float4 e = *(const float4*)&temp_emb[t * C_ + cg * 4];
    f16x4 kv;
    kv[0] = (_Float16)(v.x + e.x); kv[1] = (_Float16)(v.y + e.y);
    kv[2] = (_Float16)(v.z + e.z); kv[3] = (_Float16)(v.w + e.w);
    *(f16x4*)&kin_s[tk][cg * 4] = kv;
  }

  const int l = tid & 63, w = tid >> 6, l15 = l & 15, g = l >> 4;  // w: 0..7
  const _Float16* Wbase = WT + (size_t)(w * 48) * 128;             // 3 N-tiles

  f16x4 acur[3], anxt[3];
#pragma unroll
  for (int j = 0; j < 3; ++j)
    acur[j] = *(const f16x4*)&Wbase[(size_t)(j * 16 + l15) * 128 + 4 * g];

  __syncthreads();

  f32x4 acc[3][4];
#pragma unroll
  for (int j = 0; j < 3; ++j)
#pragma unroll
    for (int tt = 0; tt < 4; ++tt) acc[j][tt] = (f32x4){0.f, 0.f, 0.f, 0.f};

#pragma unroll
  for (int kc = 0; kc < 8; ++kc) {
    if (kc < 7) {
      const int kon = (kc + 1) * 16 + 4 * g;
#pragma unroll
      for (int j = 0; j < 3; ++j)
        anxt[j] = *(const f16x4*)&Wbase[(size_t)(j * 16 + l15) * 128 + kon];
    }
    const int ko = kc * 16 + 4 * g;
    f16x4 bfr[4];
#pragma unroll
    for (int tt = 0; tt < 4; ++tt)
      bfr[tt] = *(const f16x4*)&kin_s[tt * 16 + l15][ko];
#pragma unroll
    for (int j = 0; j < 3; ++j)
#pragma unroll
      for (int tt = 0; tt < 4; ++tt)
        acc[j][tt] = mfma16(acur[j], bfr[tt], acc[j][tt]);
#pragma unroll
    for (int j = 0; j < 3; ++j) acur[j] = anxt[j];
  }

  constexpr float CSC = 0.25f * 1.44269504088896f;
#pragma unroll
  for (int j = 0; j < 3; ++j) {
    const int ntile = w * 3 + j;                  // 0..23
    const int ch0 = (ntile & 7) * 16 + 4 * g;
#pragma unroll
    for (int tt = 0; tt < 4; ++tt) {
      const int tok = tok0 + tt * 16 + l15;
      const size_t o = (size_t)tok * CK_ + ch0;
      f16x4 r;
      if (ntile < 8) {
        const int x = tok & 127, y = (tok >> 7) & 127;
        const int cy = min(max(y, RY_), H_ - 1 - RY_);
        const int cx = min(max(x, RX_), W_ - 1 - RX_);
        const int qsp = (y - cy + RY_) * PW_ + (x - cx + RX_);
        const float4 e = *(const float4*)&spatial_emb[qsp * CK_ + ch0];
        r[0] = (_Float16)((acc[j][tt][0] + e.x) * CSC);
        r[1] = (_Float16)((acc[j][tt][1] + e.y) * CSC);
        r[2] = (_Float16)((acc[j][tt][2] + e.z) * CSC);
        r[3] = (_Float16)((acc[j][tt][3] + e.w) * CSC);
        *(f16x4*)&Qh[o] = r;
      } else if (ntile < 16) {
        r[0] = (_Float16)acc[j][tt][0]; r[1] = (_Float16)acc[j][tt][1];
        r[2] = (_Float16)acc[j][tt][2]; r[3] = (_Float16)acc[j][tt][3];
        *(f16x4*)&Kh[o] = r;
      } else {
        const float4 tve = *(const float4*)&tv[t * 128 + ch0];
        r[0] = (_Float16)(acc[j][tt][0] - tve.x);
        r[1] = (_Float16)(acc[j][tt][1] - tve.y);
        r[2] = (_Float16)(acc[j][tt][2] - tve.z);
        r[3] = (_Float16)(acc[j][tt][3] - tve.w);
        *(f16x4*)&Vh[o] = r;
      }
    }
  }
}

// ---------------------------------------------------------------------------
// Kernel B: MFMA attention v11 (R22, measured 87.6us): R17 + frame-invariant
// qe gather hoisted into 24 registers.
// ---------------------------------------------------------------------------
__global__ __launch_bounds__(256) void attn_mfma(
    const _Float16* __restrict__ Q, const _Float16* __restrict__ K,
    const _Float16* __restrict__ V, const _Float16* __restrict__ spH,
    _Float16* __restrict__ ck)
{
  __shared__ __align__(16) _Float16 K_s[192 * 40];
  __shared__ __align__(16) _Float16 V_s[192 * 44];
  __shared__ __align__(8)  _Float16 qe_s[2 * 64 * 26];  // [h][q][26]; slot25=-30000
  __shared__ float l_s[4][2][16];

  const int tid = threadIdx.x;
  const int bid0 = blockIdx.x;
  const int bid = (bid0 & 7) * 768 + (bid0 >> 3);   // bijective: 8a+b -> 768b+a
  const int hq = bid & 3;                 // head quarter: channels hq*32..+31
  const int tile = bid >> 2;
  const int tx = tile & 15, ty = (tile >> 4) & 15, img = tile >> 8;
  const int b = img / 3;
  const int y0 = ty * 8, x0 = tx * 8;
  const int rowbase = max(y0, 2) - 2;
  const int colbase = max(x0, 2) - 2;
  const int tokbase = img * 16384 + y0 * 128 + x0;
  const int chb = hq * 32;

  const int l = tid & 63, wv = tid >> 6, l15 = l & 15, g = l >> 4;
  const int q_glob = wv * 16 + l15;
  const int qy = 2 * wv + (l15 >> 3), qx = l15 & 7;
  const int y = y0 + qy, x = x0 + qx;
  const int tok = tokbase + qy * 128 + qx;
  const int cy = min(max(y, 2), 125), cx = min(max(x, 2), 125);
  const int myryc = cy - rowbase;
  const int rxc = cx - colbase;
  const int dxpbase = 4 * g - rxc + 2;

  const int rycA = min(max(y0 + 2 * wv,     2), 125) - rowbase;
  const int rycB = min(max(y0 + 2 * wv + 1, 2), 125) - rowbase;
  const int rymin = min(min(rycA, rycB) - 2, 6);

  // hoisted per-lane x-validity (fixed for whole kernel)
  bool vx[4];
#pragma unroll
  for (int i = 0; i < 4; ++i) vx[i] = (unsigned)(dxpbase + i) <= 4u;

  // ---- hoisted staging offsets (fixed across frames) ----
  int poff[6], ldoffK[6], ldoffV[6];
#pragma unroll
  for (int it = 0; it < 6; ++it) {
    const int idx = tid + it * 256;
    const int row = idx >> 3, cg = idx & 7;
    const int ny = min(rowbase + (row >> 4), 127);
    const int nx = min(colbase + (row & 15), 127);
    poff[it] = (ny * 128 + nx) * CK_ + chb + cg * 4;
    ldoffK[it] = row * 40 + cg * 4;
    ldoffV[it] = row * 44 + cg * 4;
  }
  const size_t imgstep = (size_t)16384 * CK_;
  const _Float16* Kp = K + (size_t)(b * 3) * imgstep;
  const _Float16* Vp = V + (size_t)(b * 3) * imgstep;

  // ---- prefetch frame 0 (in flight during qfrag/qe setup) ----
  f16x4 kpre[6], vpre[6];
#pragma unroll
  for (int it = 0; it < 6; ++it) {
    kpre[it] = *(const f16x4*)&Kp[poff[it]];
    vpre[it] = *(const f16x4*)&Vp[poff[it]];
  }

  // Q fragments (pre-scaled, spatial emb folded by qkv kernel)
  f16x4 qfrag[2];
#pragma unroll
  for (int h = 0; h < 2; ++h)
    qfrag[h] = *(const f16x4*)&Q[(size_t)tok * CK_ + chb + h * 16 + 4 * g];

  // qe[h][q][s] = Qs . emb_s via MFMA -> per-wave-private f16 table.
#pragma unroll
  for (int h = 0; h < 2; ++h) {
    const int qrow = (h * 64 + q_glob) * 26;
#pragma unroll
    for (int mt = 0; mt < 2; ++mt) {
      const f16x4 a = *(const f16x4*)&spH[(size_t)(mt * 16 + l15) * 128 + chb + h * 16 + 4 * g];
      f32x4 c = {0.f, 0.f, 0.f, 0.f};
      c = mfma16(a, qfrag[h], c);
      const int s0w = mt * 16 + 4 * g;       // s of c[0]
      if (mt == 0 || g < 2) {                // s0w..s0w+3 <= 23: full f16x4
        U32H2 p01, p23;
        p01.h = pkrtz(c[0], c[1]);
        p23.h = pkrtz(c[2], c[3]);
        *(unsigned*)&qe_s[qrow + s0w]     = p01.u;
        *(unsigned*)&qe_s[qrow + s0w + 2] = p23.u;
      } else if (g == 2) {                   // s = 24..27: only s=24 is real
        qe_s[qrow + 24] = (_Float16)c[0];
      }                                       // g == 3: s = 28..31, all dead
    }
  }
  // mask slot (after table writes; same-wave ordering)
  if (g == 0) {
    qe_s[(0 * 64 + q_glob) * 26 + 25] = (_Float16)(-30000.0f);
    qe_s[(1 * 64 + q_glob) * 26 + 25] = (_Float16)(-30000.0f);
  }

  // ---- FRAME-INVARIANT qe gather, hoisted: 24 regs (2h x 6jj x 2 words) ----
  unsigned qe01[2][6], qe23[2][6];
#pragma unroll
  for (int jj = 0; jj < 6; ++jj) {
    const int nt = rymin + jj;
    const int dyp = nt - myryc + 2;
    const bool vy = (unsigned)dyp <= 4u;
    const int s0 = dyp * 5 + dxpbase;
    int si[4];
#pragma unroll
    for (int i = 0; i < 4; ++i) si[i] = (vy && vx[i]) ? s0 + i : 25;
#pragma unroll
    for (int h = 0; h < 2; ++h) {
      const int qb = (h * 64 + q_glob) * 26;
      qe01[h][jj] = (unsigned)(unsigned short)__builtin_bit_cast(short, qe_s[qb + si[0]])
                  | ((unsigned)(unsigned short)__builtin_bit_cast(short, qe_s[qb + si[1]]) << 16);
      qe23[h][jj] = (unsigned)(unsigned short)__builtin_bit_cast(short, qe_s[qb + si[2]])
                  | ((unsigned)(unsigned short)__builtin_bit_cast(short, qe_s[qb + si[3]]) << 16);
    }
  }

  f32x4 o_acc[2];
  float l_acc[2];
#pragma unroll
  for (int h = 0; h < 2; ++h) { o_acc[h] = (f32x4){0.f, 0.f, 0.f, 0.f}; l_acc[h] = 0.f; }

  const f16x2 ones2 = {(_Float16)1.f, (_Float16)1.f};

#pragma unroll
  for (int t = 0; t < 3; ++t) {
    if (t) __syncthreads();           // prev-frame reads done before restage
#pragma unroll
    for (int it = 0; it < 6; ++it) {
      *(f16x4*)&K_s[ldoffK[it]] = kpre[it];
      *(f16x4*)&V_s[ldoffV[it]] = vpre[it];
    }
    __syncthreads();                  // staging visible
    if (t < 2) {                      // issue next frame's loads before compute
      const _Float16* Kt = Kp + (size_t)(t + 1) * imgstep;
      const _Float16* Vt = Vp + (size_t)(t + 1) * imgstep;
#pragma unroll
      for (int it = 0; it < 6; ++it) {
        kpre[it] = *(const f16x4*)&Kt[poff[it]];
        vpre[it] = *(const f16x4*)&Vt[poff[it]];
      }
    }

    __builtin_amdgcn_s_setprio(1);
    f16x4 wfr[2][6];
#pragma unroll
    for (int jj = 0; jj < 6; ++jj) {
      const int nt = rymin + jj;
      // both head MFMAs first
      f32x4 c0 = {0.f, 0.f, 0.f, 0.f}, c1 = {0.f, 0.f, 0.f, 0.f};
      {
        const f16x4 a0 = *(const f16x4*)&K_s[(nt * 16 + l15) * 40 + 4 * g];
        const f16x4 a1 = *(const f16x4*)&K_s[(nt * 16 + l15) * 40 + 16 + 4 * g];
        c0 = mfma16(a0, qfrag[0], c0);
        c1 = mfma16(a1, qfrag[1], c1);
      }
#pragma unroll
      for (int h = 0; h < 2; ++h) {
        const f32x4 c = h ? c1 : c0;
        U32H2 q01, q23;
        q01.u = qe01[h][jj];
        q23.u = qe23[h][jj];
        const f16x2 s01 = pkrtz(c[0], c[1]) + q01.h;
        const f16x2 s23 = pkrtz(c[2], c[3]) + q23.h;
        U32H2 p01, p23;
        p01.u = pk_exp2(s01);
        p23.u = pk_exp2(s23);
        l_acc[h] = __builtin_amdgcn_fdot2(p01.h, ones2, l_acc[h], false);
        l_acc[h] = __builtin_amdgcn_fdot2(p23.h, ones2, l_acc[h], false);
        union { unsigned u[2]; f16x4 v; } wu;
        wu.u[0] = p01.u; wu.u[1] = p23.u;
        wfr[h][jj] = wu.v;
      }
    }

    // PV: o = w . V  (w C-frag reused as A-frag; V row-major B-frags)
#pragma unroll
    for (int h = 0; h < 2; ++h) {
#pragma unroll
      for (int jj = 0; jj < 6; ++jj) {
        const int nt = rymin + jj;
        f16x4 bv;
#pragma unroll
        for (int i = 0; i < 4; ++i)
          bv[i] = V_s[(nt * 16 + 4 * g + i) * 44 + h * 16 + l15];
        o_acc[h] = mfma16(wfr[h][jj], bv, o_acc[h]);
      }
    }
    __builtin_amdgcn_s_setprio(0);
  }

  // normalize: l lives per (q=l15); o lives per (q=4g+i, ch=l15) -> via LDS
#pragma unroll
  for (int h = 0; h < 2; ++h) {
    float lt = l_acc[h];
    lt += __shfl_xor(lt, 16);
    lt += __shfl_xor(lt, 32);
    if (l < 16) l_s[wv][h][l15] = 1.f / lt;
  }
#pragma unroll
  for (int h = 0; h < 2; ++h) {
#pragma unroll
    for (int i = 0; i < 4; ++i) {
      const int q = 4 * g + i;
      const float inv = l_s[wv][h][q];
      const int qtok = tokbase + (2 * wv + (q >> 3)) * 128 + (q & 7);
      ck[(size_t)qtok * CK_ + chb + h * 16 + l15] = (_Float16)(o_acc[h][i] * inv);
    }
  }
}

// ---------------------------------------------------------------------------
// Kernel C: out = ck @ Wo via MFMA. Block = 128 tokens; wave = 2 N-tiles x 8
// token-tiles. ck_s stride 152 (bank spread ~2/bank).
// ---------------------------------------------------------------------------
__global__ __launch_bounds__(256) void out_mfma(
    const _Float16* __restrict__ ck, const _Float16* __restrict__ WoT,
    float* __restrict__ out)
{
  __shared__ __align__(16) _Float16 ck_s[128][152];
  const int tid = threadIdx.x;
  const int tok0 = blockIdx.x * 128;

  for (int i = tid; i < 128 * 16; i += 256) {
    const int tk = i >> 4, cg = i & 15;
    *(f16x8*)&ck_s[tk][cg * 8] = *(const f16x8*)&ck[(size_t)(tok0 + tk) * C_ + cg * 8];
  }
  __syncthreads();

  const int l = tid & 63, w = tid >> 6, l15 = l & 15, g = l >> 4;

  f32x4 acc[2][8];
#pragma unroll
  for (int j = 0; j < 2; ++j)
#pragma unroll
    for (int tt = 0; tt < 8; ++tt) acc[j][tt] = (f32x4){0.f, 0.f, 0.f, 0.f};

  for (int kc = 0; kc < 8; ++kc) {
    const int ko = kc * 16 + 4 * g;
    f16x4 bfr[8];
#pragma unroll
    for (int tt = 0; tt < 8; ++tt)
      bfr[tt] = *(const f16x4*)&ck_s[tt * 16 + l15][ko];
#pragma unroll
    for (int j = 0; j < 2; ++j) {
      const f16x4 a = *(const f16x4*)&WoT[(size_t)((w * 2 + j) * 16 + l15) * 128 + ko];
#pragma unroll
      for (int tt = 0; tt < 8; ++tt)
        acc[j][tt] = mfma16(a, bfr[tt], acc[j][tt]);
    }
  }

#pragma unroll
  for (int j = 0; j < 2; ++j) {
    const int ch0 = (w * 2 + j) * 16 + 4 * g;
#pragma unroll
    for (int tt = 0; tt < 8; ++tt) {
      const int tok = tok0 + tt * 16 + l15;
      float4 ov;
      ov.x = acc[j][tt][0]; ov.y = acc[j][tt][1];
      ov.z = acc[j][tt][2]; ov.w = acc[j][tt][3];
      *(float4*)&out[(size_t)tok * C_ + ch0] = ov;
    }
  }
}

// ---------------------------------------------------------------------------
extern "C" void kernel_launch(void* const* d_in, const int* in_sizes, int n_in,
                              void* d_out, int out_size, void* d_ws, size_t ws_size,
                              hipStream_t stream) {
    const float* values      = (const float*)d_in[0];
    const float* Wq          = (const float*)d_in[1];
    const float* Wk          = (const float*)d_in[2];
    const float* Wv          = (const float*)d_in[3];
    const float* Wo          = (const float*)d_in[4];
    const float* temp_emb    = (const float*)d_in[5];
    const float* spatial_emb = (const float*)d_in[6];
    float* out = (float*)d_out;

    const size_t NC = (size_t)NTOK * CK_;
    _Float16* Qh  = (_Float16*)d_ws;
    _Float16* Kh  = Qh  + NC;
    _Float16* Vh  = Kh  + NC;
    _Float16* ckh = Vh  + NC;
    _Float16* WT  = ckh + NC;          // [384][128]
    _Float16* WoT = WT  + 49152;       // [128][128]
    _Float16* spH = WoT + 16384;       // [32][128]
    float*    tv  = (float*)(spH + 4096);  // [3][128]

    prep<<<274, 256, 0, stream>>>(Wq, Wk, Wv, Wo, spatial_emb, temp_emb,
                                  WT, WoT, spH, tv);
    qkv_mfma<<<NTOK / 64, 512, 0, stream>>>(values, WT, temp_emb, spatial_emb,
                                            tv, Qh, Kh, Vh);
    attn_mfma<<<6144, 256, 0, stream>>>(Qh, Kh, Vh, spH, ckh);
    out_mfma<<<NTOK / 128, 256, 0, stream>>>(ckh, WoT, out);
}